// Round 5
// baseline (6445.212 us; speedup 1.0000x reference)
//
#include <hip/hip_runtime.h>
#include <cstdint>
#include <cstddef>

#define N_NODES_C 100000
#define N_EDGES_C 1250000
#define N_PAIRS_C 200000
#define IN_DIM_C 128
#define HID_C 64

// graph-build geometry
#define NB_S 256
#define BSH 9
#define NPB 512
#define NBKT 196
#define SEG_CAP 8192

// ---------------- scan helpers ----------------

#define SCAN_TPB 256
#define SCAN_IPT 4
#define SCAN_ELEMS 1024

__global__ void k_scan_partial(const int* __restrict__ in, int* __restrict__ outp,
                               int* __restrict__ blocksums, int n) {
    __shared__ int sd[SCAN_TPB];
    int tid = threadIdx.x;
    int base = blockIdx.x * SCAN_ELEMS + tid * SCAN_IPT;
    int v[SCAN_IPT]; int s = 0;
    for (int k = 0; k < SCAN_IPT; k++) { int idx = base + k; v[k] = (idx < n) ? in[idx] : 0; s += v[k]; }
    sd[tid] = s;
    __syncthreads();
    for (int off = 1; off < SCAN_TPB; off <<= 1) {
        int t = (tid >= off) ? sd[tid - off] : 0;
        __syncthreads();
        sd[tid] += t;
        __syncthreads();
    }
    int excl = sd[tid] - s;
    for (int k = 0; k < SCAN_IPT; k++) { int idx = base + k; if (idx < n) outp[idx] = excl; excl += v[k]; }
    if (tid == SCAN_TPB - 1) blocksums[blockIdx.x] = sd[tid];
}

__global__ void k_scan_blocks(int* __restrict__ bs, int nb) {
    __shared__ int sd[128];
    int t = threadIdx.x;
    int v = (t < nb) ? bs[t] : 0;
    sd[t] = v;
    __syncthreads();
    for (int off = 1; off < 128; off <<= 1) {
        int u = (t >= off) ? sd[t - off] : 0;
        __syncthreads();
        sd[t] += u;
        __syncthreads();
    }
    if (t < nb) bs[t] = sd[t] - v;
}

__global__ void k_scan_addg(int* __restrict__ arr, const int* __restrict__ bs, int n) {
    int i = blockIdx.x * blockDim.x + threadIdx.x;
    if (i < n) arr[i] += bs[i >> 10];
}

// ---------------- graph build: two-level counting sort ----------------

__global__ __launch_bounds__(256) void k_hist(const int* __restrict__ dst,
                                              int* __restrict__ histT, int e) {
    __shared__ int lh[NBKT];
    int tid = threadIdx.x, k = blockIdx.x;
    if (tid < NBKT) lh[tid] = 0;
    __syncthreads();
    int chunk = (e + NB_S - 1) / NB_S;
    int i0 = k * chunk, i1 = min(i0 + chunk, e);
    for (int i = i0 + tid; i < i1; i += 256) atomicAdd(&lh[dst[i] >> BSH], 1);
    __syncthreads();
    if (tid < NBKT) histT[tid * NB_S + k] = lh[tid];
}

__global__ __launch_bounds__(256) void k_scatter(const int* __restrict__ edges,
                                                 const int* __restrict__ offs,
                                                 int2* __restrict__ staging, int e) {
    __shared__ int cur[NBKT];
    int tid = threadIdx.x, k = blockIdx.x;
    if (tid < NBKT) cur[tid] = offs[tid * NB_S + k];
    __syncthreads();
    int chunk = (e + NB_S - 1) / NB_S;
    int i0 = k * chunk, i1 = min(i0 + chunk, e);
    for (int i = i0 + tid; i < i1; i += 256) {
        int s = edges[i];
        int d = edges[e + i];
        int p = atomicAdd(&cur[d >> BSH], 1);
        staging[p] = make_int2(s, d);
    }
}

__global__ __launch_bounds__(256) void k_bucket_fill(const int2* __restrict__ staging,
        const int* __restrict__ offs, int* __restrict__ rowptr,
        float* __restrict__ invd, int* __restrict__ adj, int n, int e) {
    __shared__ int ldeg[NPB];
    __shared__ int lrow[NPB];
    __shared__ int ps[256];
    __shared__ int lseg[SEG_CAP];
    int tid = threadIdx.x, b = blockIdx.x;
    int n0 = b << BSH;
    int nn = min(NPB, n - n0);
    int segBeg = offs[b * NB_S];
    int segEnd = (b == NBKT - 1) ? e : offs[(b + 1) * NB_S];

    ldeg[tid] = 0; ldeg[tid + 256] = 0;
    __syncthreads();
    for (int i = segBeg + tid; i < segEnd; i += 256)
        atomicAdd(&ldeg[staging[i].y - n0], 1);
    __syncthreads();

    int a0 = ldeg[2 * tid], a1 = ldeg[2 * tid + 1];
    int s = a0 + a1;
    ps[tid] = s;
    __syncthreads();
    for (int off = 1; off < 256; off <<= 1) {
        int t = (tid >= off) ? ps[tid - off] : 0;
        __syncthreads();
        ps[tid] += t;
        __syncthreads();
    }
    int excl = ps[tid] - s;
    lrow[2 * tid] = excl;
    lrow[2 * tid + 1] = excl + a0;
    __syncthreads();

    for (int j = tid; j < nn; j += 256) {
        rowptr[n0 + j] = segBeg + lrow[j];
        int d = ldeg[j];
        invd[n0 + j] = (d > 0) ? (1.0f / (float)d) : 0.0f;
    }
    if (b == NBKT - 1 && tid == 0) rowptr[n] = e;
    __syncthreads();

    for (int i = segBeg + tid; i < segEnd; i += 256) {
        int2 ed = staging[i];
        int p = atomicAdd(&lrow[ed.y - n0], 1);
        if (p < SEG_CAP) lseg[p] = ed.x;
        else adj[segBeg + p] = ed.x;
    }
    __syncthreads();

    int m = segEnd - segBeg; if (m > SEG_CAP) m = SEG_CAP;
    for (int p = tid; p < m; p += 256) adj[segBeg + p] = lseg[p];
}

// ---------------- aggregation ----------------

__global__ __launch_bounds__(256) void k_aggregate(const int* __restrict__ rowptr,
        const int* __restrict__ adj, const float* __restrict__ invd,
        const float* __restrict__ hin, float* __restrict__ agg, int n) {
    int wid = threadIdx.x >> 6, lane = threadIdx.x & 63;
    int node = blockIdx.x * 4 + wid;
    if (node >= n) return;
    int beg = rowptr[node], end = rowptr[node + 1];
    float acc = 0.0f;
    for (int e = beg; e < end; e += 8) {
        int idx[8];
        #pragma unroll
        for (int j = 0; j < 8; ++j) {
            int ee = e + j;
            idx[j] = adj[ee < end ? ee : end - 1];
        }
        float v[8];
        #pragma unroll
        for (int j = 0; j < 8; ++j) v[j] = hin[(size_t)idx[j] * HID_C + lane];
        #pragma unroll
        for (int j = 0; j < 8; ++j) acc += (e + j < end) ? v[j] : 0.0f;
    }
    agg[(size_t)node * HID_C + lane] = acc * invd[node];
}

// ---------------- register-direct GEMM (64 rows x 64 cols, K=128) ----------
// Thread = 4 rows x 4 cols. A-fragments loaded straight from global as float4
// along k (rows contiguous in k -> no transpose, no LDS for A, no 2nd barrier).
// 16 threads/row present identical addresses (broadcast-coalesced). W staged
// once in LDS (32 KB -> 4 blocks/CU). a_nxt/a_cur software prefetch = 1 chunk
// of latency tolerance. Per 4-k chunk/wave: 64 fma (128 cyc) vs 4 ds_read_b128
// (~48 cyc) + 4 VMEM issues -> VALU-bound.
// MODE 0: encoder (pA=x row, pB=pA+64)  MODE 1: layer (pA=agg,pB=hin)
// MODE 2: pred (pA=h[a], pB=h[b], fused @W2+b2 reduction)

__device__ __forceinline__ float4 ld4(const float* p) { return *(const float4*)p; }

template<int MODE>
__global__ __launch_bounds__(256, 4) void k_gemm(
    const float* __restrict__ A1, const float* __restrict__ A2,
    const int* __restrict__ pidx,
    const float* __restrict__ Ws1, const float* __restrict__ Ws2,
    const float* __restrict__ bias, const float* __restrict__ W2p,
    const float* __restrict__ b2p,
    float* __restrict__ outp, int nrows)
{
    __shared__ float Wm[128 * 64];   // 32 KB, k-major
    const int t = threadIdx.x;
    const int g0 = blockIdx.x * 64;

    #pragma unroll
    for (int p = 0; p < 8; ++p) {
        int k = p * 16 + (t >> 4);
        int c4 = (t & 15) * 4;
        float4 wv;
        if (MODE == 1) wv = (k < 64) ? ld4(Ws1 + k * 64 + c4) : ld4(Ws2 + (k - 64) * 64 + c4);
        else           wv = ld4(Ws1 + k * 64 + c4);
        *(float4*)&Wm[k * 64 + c4] = wv;
    }
    __syncthreads();

    const int tc = t & 15, tr = t >> 4;
    const int tc4 = tc * 4, tr4 = tr * 4;

    const float* pA[4]; const float* pB[4];
    #pragma unroll
    for (int i = 0; i < 4; ++i) {
        int g = g0 + tr4 + i; if (g > nrows - 1) g = nrows - 1;
        if (MODE == 0)      { pA[i] = A1 + (size_t)g * 128; pB[i] = pA[i] + 64; }
        else if (MODE == 1) { pA[i] = A1 + (size_t)g * 64;  pB[i] = A2 + (size_t)g * 64; }
        else { int ia = pidx[2 * g], ib = pidx[2 * g + 1];
               pA[i] = A1 + (size_t)ia * 64; pB[i] = A1 + (size_t)ib * 64; }
    }

    float4 acc[4];
    #pragma unroll
    for (int i = 0; i < 4; ++i) acc[i] = make_float4(0.f, 0.f, 0.f, 0.f);

    float4 a_cur[4], a_nxt[4];
    #pragma unroll
    for (int i = 0; i < 4; ++i) a_cur[i] = ld4(pA[i]);

    // half 0: k = 0..63
    #pragma unroll
    for (int c = 0; c < 16; ++c) {
        #pragma unroll
        for (int i = 0; i < 4; ++i)
            a_nxt[i] = (c < 15) ? ld4(pA[i] + (c + 1) * 4) : ld4(pB[i]);
        #pragma unroll
        for (int kk = 0; kk < 4; ++kk) {
            float4 w = ld4(&Wm[(4 * c + kk) * 64 + tc4]);
            #pragma unroll
            for (int i = 0; i < 4; ++i) {
                float a = ((const float*)&a_cur[i])[kk];
                acc[i].x = fmaf(a, w.x, acc[i].x);
                acc[i].y = fmaf(a, w.y, acc[i].y);
                acc[i].z = fmaf(a, w.z, acc[i].z);
                acc[i].w = fmaf(a, w.w, acc[i].w);
            }
        }
        #pragma unroll
        for (int i = 0; i < 4; ++i) a_cur[i] = a_nxt[i];
    }
    // half 1: k = 64..127
    #pragma unroll
    for (int c = 0; c < 16; ++c) {
        #pragma unroll
        for (int i = 0; i < 4; ++i)
            a_nxt[i] = (c < 15) ? ld4(pB[i] + (c + 1) * 4) : make_float4(0.f, 0.f, 0.f, 0.f);
        #pragma unroll
        for (int kk = 0; kk < 4; ++kk) {
            float4 w = ld4(&Wm[(64 + 4 * c + kk) * 64 + tc4]);
            #pragma unroll
            for (int i = 0; i < 4; ++i) {
                float a = ((const float*)&a_cur[i])[kk];
                acc[i].x = fmaf(a, w.x, acc[i].x);
                acc[i].y = fmaf(a, w.y, acc[i].y);
                acc[i].z = fmaf(a, w.z, acc[i].z);
                acc[i].w = fmaf(a, w.w, acc[i].w);
            }
        }
        #pragma unroll
        for (int i = 0; i < 4; ++i) a_cur[i] = a_nxt[i];
    }

    float4 bv = ld4(bias + tc4);
    if (MODE == 2) {
        float4 w2 = ld4(W2p + tc4);
        float bb = b2p[0];
        #pragma unroll
        for (int i = 0; i < 4; ++i) {
            float zx = fmaxf(acc[i].x + bv.x, 0.f);
            float zy = fmaxf(acc[i].y + bv.y, 0.f);
            float zz = fmaxf(acc[i].z + bv.z, 0.f);
            float zw = fmaxf(acc[i].w + bv.w, 0.f);
            float v = zx * w2.x + zy * w2.y + zz * w2.z + zw * w2.w;
            v += __shfl_down(v, 8, 64);
            v += __shfl_down(v, 4, 64);
            v += __shfl_down(v, 2, 64);
            v += __shfl_down(v, 1, 64);
            if (tc == 0) {
                int g = g0 + tr4 + i;
                if (g < nrows) outp[g] = v + bb;
            }
        }
    } else {
        #pragma unroll
        for (int i = 0; i < 4; ++i) {
            int g = g0 + tr4 + i;
            if (g < nrows) {
                float4 o;
                o.x = fmaxf(acc[i].x + bv.x, 0.f);
                o.y = fmaxf(acc[i].y + bv.y, 0.f);
                o.z = fmaxf(acc[i].z + bv.z, 0.f);
                o.w = fmaxf(acc[i].w + bv.w, 0.f);
                *(float4*)&outp[(size_t)g * 64 + tc4] = o;
            }
        }
    }
}

// ---------------- launch ----------------

extern "C" void kernel_launch(void* const* d_in, const int* in_sizes, int n_in,
                              void* d_out, int out_size, void* d_ws, size_t ws_size,
                              hipStream_t stream) {
    const float* x    = (const float*)d_in[0];
    const int*   edges= (const int*)d_in[1];
    const int*   pair = (const int*)d_in[2];
    const float* encW = (const float*)d_in[3];
    const float* encb = (const float*)d_in[4];
    const float* Wl   = (const float*)d_in[5];
    const float* bl   = (const float*)d_in[6];
    const float* Wr   = (const float*)d_in[7];
    const float* W1   = (const float*)d_in[8];
    const float* b1   = (const float*)d_in[9];
    const float* W2   = (const float*)d_in[10];
    const float* b2   = (const float*)d_in[11];
    float* out = (float*)d_out;

    const int N = N_NODES_C, E = N_EDGES_C, P = N_PAIRS_C;
    const int* dst = edges + E;
    const int M = NBKT * NB_S;

    char* w = (char*)d_ws;
    auto alloc = [&](size_t bytes) { char* p = w; w += (bytes + 255) & ~(size_t)255; return p; };
    int*   rowptr = (int*)alloc((size_t)(N + 1) * 4);
    int*   histT  = (int*)alloc((size_t)M * 4);
    int*   offs   = (int*)alloc((size_t)M * 4);
    int*   bsums  = (int*)alloc(128 * 4);
    float* invd   = (float*)alloc((size_t)N * 4);
    int*   adj    = (int*)alloc((size_t)E * 4);
    float* h0     = (float*)alloc((size_t)N * HID_C * 4);
    float* h1     = (float*)alloc((size_t)N * HID_C * 4);
    float* agg    = (float*)alloc((size_t)N * HID_C * 4);
    int2*  staging= (int2*)agg;

    int nscan = (M + SCAN_ELEMS - 1) / SCAN_ELEMS;

    hipLaunchKernelGGL(k_hist, dim3(NB_S), dim3(256), 0, stream, dst, histT, E);
    hipLaunchKernelGGL(k_scan_partial, dim3(nscan), dim3(SCAN_TPB), 0, stream, histT, offs, bsums, M);
    hipLaunchKernelGGL(k_scan_blocks, dim3(1), dim3(128), 0, stream, bsums, nscan);
    hipLaunchKernelGGL(k_scan_addg, dim3((M + 255) / 256), dim3(256), 0, stream, offs, bsums, M);
    hipLaunchKernelGGL(k_scatter, dim3(NB_S), dim3(256), 0, stream, edges, offs, staging, E);
    hipLaunchKernelGGL(k_bucket_fill, dim3(NBKT), dim3(256), 0, stream, staging, offs, rowptr, invd, adj, N, E);

    const int NB_N = (N + 63) / 64;
    const int NB_P = (P + 63) / 64;

    k_gemm<0><<<dim3(NB_N), dim3(256), 0, stream>>>(
        x, nullptr, nullptr, encW, nullptr, encb, nullptr, nullptr, h0, N);

    float* hc = h0; float* hn = h1;
    for (int l = 0; l < 3; l++) {
        hipLaunchKernelGGL(k_aggregate, dim3((N + 3) / 4), dim3(256), 0, stream,
                           rowptr, adj, invd, hc, agg, N);
        k_gemm<1><<<dim3(NB_N), dim3(256), 0, stream>>>(
            agg, hc, nullptr, Wl + (size_t)l * 64 * 64, Wr + (size_t)l * 64 * 64,
            bl + (size_t)l * 64, nullptr, nullptr, hn, N);
        float* tswap = hc; hc = hn; hn = tswap;
    }

    k_gemm<2><<<dim3(NB_P), dim3(256), 0, stream>>>(
        hc, nullptr, pair, W1, nullptr, b1, W2, b2, out, P);
}